// Round 11
// baseline (563.178 us; speedup 1.0000x reference)
//
#include <hip/hip_runtime.h>
#include <hip/hip_bf16.h>
#include <hip/hip_fp8.h>
#include <hip/hip_cooperative_groups.h>

namespace cg = cooperative_groups;

#define N_ROWS 8192
#define NZ 16384           // rows of Z = [An; Bn]
#define DIM 256
#define TAU_INV 2.0f
#define BT 128             // block tile (square)
#define BK 128             // K-step (2 iterations over DIM=256)
#define NTILE 128          // NZ / BT
#define NTRI (NTILE * (NTILE + 1) / 2)   // 8256 upper-tri tiles
#define NCHUNK 16

typedef float f32x4 __attribute__((ext_vector_type(4)));
typedef long fp8x8;        // 8 fp8 values in 2 VGPRs (i64 MFMA operand)

// ---------------------------------------------------------------------------
__device__ __forceinline__ float wave_sum(float v) {
    #pragma unroll
    for (int m = 1; m < 64; m <<= 1) v += __shfl_xor(v, m, 64);
    return v;
}

// One WAVE per row: L2-normalize, scale by 16, quantize to fp8 e4m3;
// pos[row] = (1/256)*dot(quantized an, bn).
__device__ __forceinline__ void normalize_row(
    const float* __restrict__ z1, const float* __restrict__ z2,
    unsigned char* __restrict__ Z8, float* __restrict__ pos, int row)
{
    const int lane = threadIdx.x & 63;
    const float4 a = ((const float4*)(z1 + (size_t)row * DIM))[lane];
    const float4 b = ((const float4*)(z2 + (size_t)row * DIM))[lane];
    const float na2 = wave_sum(a.x*a.x + a.y*a.y + a.z*a.z + a.w*a.w);
    const float nb2 = wave_sum(b.x*b.x + b.y*b.y + b.z*b.z + b.w*b.w);
    const float sa = 16.0f / sqrtf(na2);   // norms ~16; eps never binds
    const float sb = 16.0f / sqrtf(nb2);
    const float av[4] = {a.x*sa, a.y*sa, a.z*sa, a.w*sa};
    const float bv[4] = {b.x*sb, b.y*sb, b.z*sb, b.w*sb};
    unsigned char pa[4], pb[4];
    float qd = 0.0f;
    #pragma unroll
    for (int k = 0; k < 4; ++k) {
        __hip_fp8_e4m3 qa(av[k]);
        __hip_fp8_e4m3 qb(bv[k]);
        pa[k] = qa.__x; pb[k] = qb.__x;
        qd += float(qa) * float(qb);
    }
    *(uchar4*)(Z8 + (size_t)row * DIM + lane * 4) = *(uchar4*)pa;
    *(uchar4*)(Z8 + (size_t)(N_ROWS + row) * DIM + lane * 4) = *(uchar4*)pb;
    qd = wave_sum(qd);
    if (lane == 0) pos[row] = qd * 0.00390625f;
}

// ---------------------------------------------------------------------------
// One 128x128 upper-triangular gram tile (fp8 MFMA, BK=128 -> 2 K-steps,
// 3 barriers/tile). LDS[r][p8] = glob[r][p8 ^ ((r>>1)&7)] (8B groups) via
// width-4 global_load_lds; frag b64 reads use the same key -> measured-zero
// conflict pattern (R10). Staging offsets are literal XOR/adds off one
// per-lane base (cuts R10's per-instr 64-bit address rebuild).
// Epilogue: exp2, diag mask, 512 coalesced part floats (NO atomics).
// ---------------------------------------------------------------------------
__device__ void gram_tile(const unsigned char* __restrict__ Z,
                          float* __restrict__ part, int bid)
{
    __shared__ unsigned char As[BT * BK];   // 16 KB
    __shared__ unsigned char Bs[BT * BK];   // 16 KB

    // triangular decode: P(ti) = ti*(257-ti)/2
    int ti = (int)((257.0f - sqrtf(66049.0f - 8.0f * (float)bid)) * 0.5f);
    ti = ti < 0 ? 0 : (ti > 127 ? 127 : ti);
    while (ti * (257 - ti) / 2 > bid) --ti;
    while ((ti + 1) * (256 - ti) / 2 <= bid) ++ti;
    const int tj = ti + (bid - ti * (257 - ti) / 2);
    const bool diag = (ti == tj);

    const int tid  = threadIdx.x;
    const int wave = tid >> 6;
    const int lane = tid & 63;
    const int wr = wave >> 1, wc = wave & 1;
    const int lm = lane & 15, lq = lane >> 4;

    // staging lane geometry: one instr = 2 rows x 128B (64 lanes x 4B)
    const int l2  = lane >> 5;              // row within pair
    const int p16 = (lane >> 1) & 15;       // 8B-group position 0..15
    const int h4  = (lane & 1) << 2;        // 0 or 4
    const int px  = p16 << 3;

    const unsigned char* gA0 =
        Z + (size_t)(ti * BT + wave * 32 + l2) * DIM + h4;
    const unsigned char* gB0 =
        Z + (size_t)(tj * BT + wave * 32 + l2) * DIM + h4;

    f32x4 acc[4][4] = {};

    for (int k0 = 0; k0 < DIM; k0 += BK) {
        if (k0) __syncthreads();        // protect LDS being read (prev k0)
        #pragma unroll
        for (int c = 0; c < 16; ++c) {  // 64 chunks of 2 rows, 16 per wave
            const int ch = wave * 16 + c;                   // wave-uniform
            const int off = (px ^ ((c & 7) << 3)) + c * 512 + k0;
            __builtin_amdgcn_global_load_lds(
                (const __attribute__((address_space(1))) void*)(gA0 + off),
                (__attribute__((address_space(3))) void*)(As + ch * 256),
                4, 0, 0);
            __builtin_amdgcn_global_load_lds(
                (const __attribute__((address_space(1))) void*)(gB0 + off),
                (__attribute__((address_space(3))) void*)(Bs + ch * 256),
                4, 0, 0);
        }
        __syncthreads();

        #pragma unroll
        for (int kk = 0; kk < 4; ++kk) {
            const int gg = kk * 4 + lq;                 // 8B group 0..15
            const int goff = (gg ^ (lm >> 1)) << 3;     // key=(row>>1)&7
            fp8x8 af[4], bf[4];
            #pragma unroll
            for (int f = 0; f < 4; ++f) {
                const int ra = wr * 64 + f * 16 + lm;
                const int rb = wc * 64 + f * 16 + lm;
                af[f] = *(const fp8x8*)(As + ra * BK + goff);
                bf[f] = *(const fp8x8*)(Bs + rb * BK + goff);
            }
            #pragma unroll
            for (int fr = 0; fr < 4; ++fr)
                #pragma unroll
                for (int fc = 0; fc < 4; ++fc)
                    acc[fr][fc] = __builtin_amdgcn_mfma_f32_16x16x32_fp8_fp8(
                        af[fr], bf[fc], acc[fr][fc], 0, 0, 0);
        }
    }
    // no trailing barrier: epilogue is register-only; caller syncs per tile

    // dot = 256*sim; exp(2*sim) = exp2(dot * 2*log2(e)/256)
    const float SC = 2.8853900817779268f / 256.0f;
    #pragma unroll
    for (int fr = 0; fr < 4; ++fr)
        #pragma unroll
        for (int fc = 0; fc < 4; ++fc)
            #pragma unroll
            for (int r = 0; r < 4; ++r)
                acc[fr][fc][r] = exp2f(acc[fr][fc][r] * SC);

    if (diag) {   // zero at-or-below-diagonal (each pair counted once)
        #pragma unroll
        for (int fr = 0; fr < 4; ++fr) {
            const int gi = wr * 64 + fr * 16 + lq * 4;
            #pragma unroll
            for (int fc = 0; fc < 4; ++fc) {
                const int gj = wc * 64 + fc * 16 + lm;
                #pragma unroll
                for (int r = 0; r < 4; ++r)
                    if (gj <= gi + r) acc[fr][fc][r] = 0.0f;
            }
        }
    }

    float* dst = part + (size_t)bid * 512;

    // row partials (C/D: col=lane&15, row=lq*4+reg)
    #pragma unroll
    for (int fr = 0; fr < 4; ++fr)
        #pragma unroll
        for (int r = 0; r < 4; ++r) {
            float s = acc[fr][0][r] + acc[fr][1][r] + acc[fr][2][r] + acc[fr][3][r];
            s += __shfl_xor(s, 1, 64);
            s += __shfl_xor(s, 2, 64);
            s += __shfl_xor(s, 4, 64);
            s += __shfl_xor(s, 8, 64);
            if (lm == 0)
                dst[wc * 128 + wr * 64 + fr * 16 + lq * 4 + r] = s;
        }
    // col partials (symmetry: colsum feeds S too)
    #pragma unroll
    for (int fc = 0; fc < 4; ++fc) {
        float s = 0.0f;
        #pragma unroll
        for (int fr = 0; fr < 4; ++fr)
            #pragma unroll
            for (int r = 0; r < 4; ++r) s += acc[fr][fc][r];
        s += __shfl_xor(s, 16, 64);
        s += __shfl_xor(s, 32, 64);
        if (lq == 0)
            dst[256 + wr * 128 + wc * 64 + fc * 16 + lm] = s;
    }
}

// ---------------------------------------------------------------------------
// Partial gather: virtual block vb in [0, 64*NCHUNK). Each Z-row has 258
// strips (row-side tj=tr..127, col-side ti=0..tr), all coalesced.
// ---------------------------------------------------------------------------
__device__ void reduce_body(const float* __restrict__ part,
                            float* __restrict__ S2, int vb)
{
    const int chunk = vb >> 6;
    const int r = (vb & 63) * 256 + threadIdx.x;    // Z row
    const int tr = r >> 7, rr = r & 127;
    const int baseRow = tr * (257 - tr) / 2;
    const int cntRow = 2 * (128 - tr);

    float s = 0.0f;
    for (int m = chunk; m < 258; m += NCHUNK) {
        size_t addr;
        if (m < cntRow) {
            const int bb = baseRow + (m >> 1);
            addr = (size_t)bb * 512 + (m & 1) * 128 + rr;
        } else {
            const int m2 = m - cntRow;
            const int tiq = m2 >> 1;
            const int bb = tiq * (257 - tiq) / 2 + (tr - tiq);
            addr = (size_t)bb * 512 + 256 + (m2 & 1) * 128 + rr;
        }
        s += part[addr];
    }
    S2[(size_t)chunk * NZ + r] = s;
}

__device__ __forceinline__ float loss_row(const float* __restrict__ S2,
                                          const float* __restrict__ pos, int i)
{
    float den1 = 0.0f, den2 = 0.0f;
    #pragma unroll
    for (int c = 0; c < NCHUNK; ++c) {
        den1 += S2[(size_t)c * NZ + i];
        den2 += S2[(size_t)c * NZ + N_ROWS + i];
    }
    return 0.5f * (logf(den1) + logf(den2)) - TAU_INV * pos[i];
}

// ---------------------------------------------------------------------------
// Fused cooperative kernel: normalize -> gram (ticket work-stealing) ->
// reduce -> loss. One dispatch, three grid syncs.
// ---------------------------------------------------------------------------
__global__ __launch_bounds__(256, 4) void fused_kernel(
    const float* __restrict__ z1, const float* __restrict__ z2,
    unsigned char* __restrict__ Z8, float* __restrict__ pos,
    float* __restrict__ S2, float* __restrict__ part,
    float* __restrict__ out, int* __restrict__ ticket)
{
    cg::grid_group grid = cg::this_grid();
    const int G = gridDim.x;
    const int tid = threadIdx.x;
    const int wave = tid >> 6;

    // ---- phase 1: normalize + zero control state (ws is poisoned 0xAA) ----
    if (blockIdx.x == 0 && tid == 0) { *ticket = 0; *out = 0.0f; }
    for (int row = blockIdx.x * 4 + wave; row < N_ROWS; row += G * 4)
        normalize_row(z1, z2, Z8, pos, row);

    grid.sync();

    // ---- phase 2: gram, atomic-ticket work stealing ----
    __shared__ int curT;
    for (;;) {
        if (tid == 0) curT = atomicAdd(ticket, 1);
        __syncthreads();                 // also orders prev tile's LDS reads
        const int t = curT;              // before next staging
        if (t >= NTRI) break;
        gram_tile(Z8, part, t);
    }

    grid.sync();

    // ---- phase 3: reduce partials ----
    for (int vb = blockIdx.x; vb < 64 * NCHUNK; vb += G)
        reduce_body(part, S2, vb);

    grid.sync();

    // ---- phase 4: loss + mean ----
    float v = 0.0f;
    for (int i = blockIdx.x * 256 + tid; i < N_ROWS; i += G * 256)
        v += loss_row(S2, pos, i);
    __shared__ float red[4];
    v = wave_sum(v);
    if ((tid & 63) == 0) red[tid >> 6] = v;
    __syncthreads();
    if (tid == 0)
        atomicAdd(out, (red[0] + red[1] + red[2] + red[3]) * (1.0f / N_ROWS));
}

// ---------------------------------------------------------------------------
// Fallback (only if ws too small for part): classic 4-dispatch pipeline.
// ---------------------------------------------------------------------------
__global__ __launch_bounds__(256) void k_norm(
    const float* __restrict__ z1, const float* __restrict__ z2,
    unsigned char* __restrict__ Z8, float* __restrict__ pos)
{
    normalize_row(z1, z2, Z8, pos, blockIdx.x * 4 + (threadIdx.x >> 6));
}
__global__ __launch_bounds__(256, 4) void k_gram(
    const unsigned char* __restrict__ Z, float* __restrict__ part)
{
    const int bid = (blockIdx.x & 7) * (NTRI / 8) + (blockIdx.x >> 3);
    gram_tile(Z, part, bid);
}
__global__ __launch_bounds__(256) void k_reduce(
    const float* __restrict__ part, float* __restrict__ S2,
    float* __restrict__ out)
{
    if (blockIdx.x == 0 && blockIdx.y == 0 && threadIdx.x == 0) out[0] = 0.0f;
    reduce_body(part, S2, blockIdx.y * 64 + blockIdx.x);
}
__global__ __launch_bounds__(256) void k_loss(
    const float* __restrict__ S2, const float* __restrict__ pos,
    float* __restrict__ out)
{
    float v = loss_row(S2, pos, blockIdx.x * 256 + threadIdx.x);
    __shared__ float red[4];
    v = wave_sum(v);
    if ((threadIdx.x & 63) == 0) red[threadIdx.x >> 6] = v;
    __syncthreads();
    if (threadIdx.x == 0)
        atomicAdd(out, (red[0] + red[1] + red[2] + red[3]) * (1.0f / N_ROWS));
}

// ---------------------------------------------------------------------------
extern "C" void kernel_launch(void* const* d_in, const int* in_sizes, int n_in,
                              void* d_out, int out_size, void* d_ws, size_t ws_size,
                              hipStream_t stream)
{
    const float* z1 = (const float*)d_in[0];
    const float* z2 = (const float*)d_in[1];
    float* out = (float*)d_out;

    char* ws = (char*)d_ws;
    unsigned char* Z8 = (unsigned char*)ws;              // 4 MB
    float* pos  = (float*)(ws + 4194304);                // 32 KB
    float* S2   = (float*)(ws + 4227072);                // 1 MB
    int*   ticket = (int*)(ws + 5275648);                // 256 B ctrl
    float* part = (float*)(ws + 5275904);                // 8256*512*4 = 16.9 MB
    const size_t need = 5275904 + (size_t)NTRI * 512 * 4;

    if (ws_size >= need) {
        int occ = 0;
        hipOccupancyMaxActiveBlocksPerMultiprocessor(&occ, fused_kernel, 256, 0);
        if (occ < 1) occ = 1;
        if (occ > 4) occ = 4;
        int grid = 256 * occ;
        void* args[] = { (void*)&z1, (void*)&z2, (void*)&Z8, (void*)&pos,
                         (void*)&S2, (void*)&part, (void*)&out, (void*)&ticket };
        hipLaunchCooperativeKernel((const void*)fused_kernel, dim3(grid),
                                   dim3(256), args, 0, stream);
    } else {
        k_norm<<<N_ROWS / 4, 256, 0, stream>>>(z1, z2, Z8, pos);
        k_gram<<<NTRI, 256, 0, stream>>>(Z8, (float*)(ws + 4227072 + 1048576));
        dim3 rg(64, NCHUNK);
        k_reduce<<<rg, 256, 0, stream>>>(part, S2, out);
        k_loss<<<N_ROWS / 256, 256, 0, stream>>>(S2, pos, out);
    }
}

// Round 12
// 319.545 us; speedup vs baseline: 1.7624x; 1.7624x over previous
//
#include <hip/hip_runtime.h>
#include <hip/hip_bf16.h>
#include <hip/hip_fp8.h>

#define N_ROWS 8192
#define NZ 16384           // rows of Z = [An; Bn]
#define DIM 256
#define TAU_INV 2.0f
#define BT 128             // block tile (square)
#define NTILE 128          // NZ / BT
#define NTRI (NTILE * (NTILE + 1) / 2)   // 8256 upper-tri tiles
#define NBAND 8

typedef float f32x4 __attribute__((ext_vector_type(4)));
typedef long lx2 __attribute__((ext_vector_type(2)));   // 16B = 2 MFMA fp8 operands

// ---------------------------------------------------------------------------
// Kernel 1: one WAVE per row. L2-normalize, scale by 16, quantize to OCP fp8
// e4m3, and write Z8 with a K-INTERLEAVED layout: each 64B chunk stores the
// eight 8B K-groups as [g0 g4 g1 g5 g2 g6 g3 g7], so one 16B granule = the
// operand pair (g, g+4) a lane needs for two consecutive MFMA K-steps.
// K-permutation is correctness-neutral (same permutation for A and B).
// pos[i] = (1/256)*dot(quantized an, bn). Also zeroes S8 (8*16384 floats)
// and out[0].
// ---------------------------------------------------------------------------
__global__ __launch_bounds__(256) void normalize_kernel(
    const float* __restrict__ z1, const float* __restrict__ z2,
    unsigned char* __restrict__ Z8, float* __restrict__ pos,
    float* __restrict__ S8, float* __restrict__ out)
{
    const int tid = threadIdx.x;
    if (blockIdx.x < 512) S8[blockIdx.x * 256 + tid] = 0.0f;   // 131072 floats
    if (blockIdx.x == 0 && tid == 0) out[0] = 0.0f;

    const int wave = tid >> 6;
    const int lane = tid & 63;
    const int row = blockIdx.x * 4 + wave;      // 0..8191

    const float4 a = ((const float4*)(z1 + (size_t)row * DIM))[lane];
    const float4 b = ((const float4*)(z2 + (size_t)row * DIM))[lane];

    auto wsum = [&](float v) -> float {
        #pragma unroll
        for (int m = 1; m < 64; m <<= 1) v += __shfl_xor(v, m, 64);
        return v;
    };

    const float na2 = wsum(a.x*a.x + a.y*a.y + a.z*a.z + a.w*a.w);
    const float nb2 = wsum(b.x*b.x + b.y*b.y + b.z*b.z + b.w*b.w);
    const float sa = 16.0f / sqrtf(na2);   // norms ~16; eps never binds
    const float sb = 16.0f / sqrtf(nb2);

    const float av[4] = {a.x*sa, a.y*sa, a.z*sa, a.w*sa};
    const float bv[4] = {b.x*sb, b.y*sb, b.z*sb, b.w*sb};
    unsigned char pa[4], pb[4];
    float qd = 0.0f;
    #pragma unroll
    for (int k = 0; k < 4; ++k) {
        __hip_fp8_e4m3 qa(av[k]);
        __hip_fp8_e4m3 qb(bv[k]);
        pa[k] = qa.__x; pb[k] = qb.__x;
        qd += float(qa) * float(qb);
    }
    // interleaved write position: lane owns half (lane&1) of K-group (lane>>1)
    const int g  = (lane >> 1) & 7;                    // group within chunk
    const int pp = ((g & 3) << 1) | (g >> 2);          // interleaved 8B slot
    const int off = (lane >> 4) * 64 + pp * 8 + (lane & 1) * 4;
    *(uchar4*)(Z8 + (size_t)row * DIM + off) = *(uchar4*)pa;
    *(uchar4*)(Z8 + (size_t)(N_ROWS + row) * DIM + off) = *(uchar4*)pb;

    qd = wsum(qd);
    if (lane == 0) pos[row] = qd * 0.00390625f;   // /256 -> quantized sim
}

// ---------------------------------------------------------------------------
// Kernel 2: symmetric fp8 gram, upper triangle, dense triangular grid.
// Block tile 128x128, 4 waves 2x2, wave tile 64x64 (4x4 frags of
// mfma_f32_16x16x32_fp8_fp8). BK=128 -> 2 K-steps, 3 barriers/tile.
// LDS 32 KB (A 16K + B 16K), row stride 128B, 16B-granule XOR swizzle
// slot = G ^ ((row>>1)&7). Staging: width-16 global_load_lds (16 instrs per
// wave per tile, vs 64 width-4 in R10 -> the VALU fix). Frag reads:
// ds_read_b128, one per TWO K-steps, addresses invariant across k0.
// Epilogue: exp2, diag mask, atomicAdd into the block's BAND replica of S
// (8 replicas kill R9's cross-XCD line ping-pong).
// __launch_bounds__(256,4): the proven 128-unified-reg no-spill tier.
// ---------------------------------------------------------------------------
__global__ __launch_bounds__(256, 4) void gram_kernel(
    const unsigned char* __restrict__ Z, float* __restrict__ S8)
{
    // XCD band remap (8256 = 8 * 1032), then triangular decode.
    const int band = blockIdx.x & 7;
    const int bid = band * (NTRI / 8) + (blockIdx.x >> 3);
    int ti = (int)((257.0f - sqrtf(66049.0f - 8.0f * (float)bid)) * 0.5f);
    ti = ti < 0 ? 0 : (ti > 127 ? 127 : ti);
    while (ti * (257 - ti) / 2 > bid) --ti;
    while ((ti + 1) * (256 - ti) / 2 <= bid) ++ti;
    const int tj = ti + (bid - ti * (257 - ti) / 2);
    const bool diag = (ti == tj);

    __shared__ unsigned char Ls[32768];   // A: [0,16K), B: [16K,32K)

    const int tid  = threadIdx.x;
    const int wave = tid >> 6;
    const int lane = tid & 63;
    const int wr = wave >> 1, wc = wave & 1;
    const int lm = lane & 15, lq = lane >> 4;

    // ---- staging lane geometry (width-16: 1KB instr = 8 rows x 8 granules)
    const int r8 = lane >> 3;                   // row within 8-row group
    const int pg = lane & 7;                    // LDS granule slot
    const int G0 = pg ^ (r8 >> 1);              // global granule, even instrs
    const int dlt = 64 - ((G0 & 4) << 5);       // +-64: odd instrs use G0^4
    const unsigned char* pAE =
        Z + (size_t)(ti * BT + wave * 32 + r8) * DIM + (G0 << 4);
    const unsigned char* pBE =
        Z + (size_t)(tj * BT + wave * 32 + r8) * DIM + (G0 << 4);
    const unsigned char* pAO = pAE + dlt;
    const unsigned char* pBO = pBE + dlt;

    // ---- frag-read bases (invariant across the whole tile)
    const int s0 = (lq ^ (lm >> 1)) << 4;       // slot for granule lq
    const int s1 = s0 ^ 64;                     // slot for granule lq+4
    const unsigned char* LA0 = Ls + wr * 8192 + lm * 128 + s0;
    const unsigned char* LA1 = Ls + wr * 8192 + lm * 128 + s1;
    const unsigned char* LB0 = Ls + 16384 + wc * 8192 + lm * 128 + s0;
    const unsigned char* LB1 = Ls + 16384 + wc * 8192 + lm * 128 + s1;

    f32x4 acc[4][4] = {};

    #pragma unroll
    for (int kh = 0; kh < 2; ++kh) {
        if (kh) __syncthreads();        // protect LDS reads of prev k-half
        #pragma unroll
        for (int c = 0; c < 4; ++c) {   // 4 A + 4 B instrs per wave
            const int ld = (wave * 4 + c) * 1024;       // wave-uniform dest
            const unsigned char* ga = ((c & 1) ? pAO : pAE) + c * 2048 + kh * 128;
            const unsigned char* gb = ((c & 1) ? pBO : pBE) + c * 2048 + kh * 128;
            __builtin_amdgcn_global_load_lds(
                (const __attribute__((address_space(1))) void*)ga,
                (__attribute__((address_space(3))) void*)(Ls + ld), 16, 0, 0);
            __builtin_amdgcn_global_load_lds(
                (const __attribute__((address_space(1))) void*)gb,
                (__attribute__((address_space(3))) void*)(Ls + 16384 + ld), 16, 0, 0);
        }
        __syncthreads();

        lx2 aP[4], bP[4];
        #pragma unroll
        for (int f = 0; f < 4; ++f) {
            aP[f] = *(const lx2*)(LA0 + f * 2048);
            bP[f] = *(const lx2*)(LB0 + f * 2048);
        }
        #pragma unroll
        for (int fr = 0; fr < 4; ++fr)
            #pragma unroll
            for (int fc = 0; fc < 4; ++fc) {
                acc[fr][fc] = __builtin_amdgcn_mfma_f32_16x16x32_fp8_fp8(
                    aP[fr].x, bP[fc].x, acc[fr][fc], 0, 0, 0);
                acc[fr][fc] = __builtin_amdgcn_mfma_f32_16x16x32_fp8_fp8(
                    aP[fr].y, bP[fc].y, acc[fr][fc], 0, 0, 0);
            }
        #pragma unroll
        for (int f = 0; f < 4; ++f) {
            aP[f] = *(const lx2*)(LA1 + f * 2048);
            bP[f] = *(const lx2*)(LB1 + f * 2048);
        }
        #pragma unroll
        for (int fr = 0; fr < 4; ++fr)
            #pragma unroll
            for (int fc = 0; fc < 4; ++fc) {
                acc[fr][fc] = __builtin_amdgcn_mfma_f32_16x16x32_fp8_fp8(
                    aP[fr].x, bP[fc].x, acc[fr][fc], 0, 0, 0);
                acc[fr][fc] = __builtin_amdgcn_mfma_f32_16x16x32_fp8_fp8(
                    aP[fr].y, bP[fc].y, acc[fr][fc], 0, 0, 0);
            }
    }
    // epilogue is LDS-free: no trailing barrier

    // dot = 256*sim; exp(2*sim) = exp2(dot * 2*log2(e)/256)
    const float SC = 2.8853900817779268f / 256.0f;
    #pragma unroll
    for (int fr = 0; fr < 4; ++fr)
        #pragma unroll
        for (int fc = 0; fc < 4; ++fc)
            #pragma unroll
            for (int r = 0; r < 4; ++r)
                acc[fr][fc][r] = exp2f(acc[fr][fc][r] * SC);

    if (diag) {   // zero at-or-below-diagonal (each pair counted once)
        #pragma unroll
        for (int fr = 0; fr < 4; ++fr) {
            const int gi = wr * 64 + fr * 16 + lq * 4;
            #pragma unroll
            for (int fc = 0; fc < 4; ++fc) {
                const int gj = wc * 64 + fc * 16 + lm;
                #pragma unroll
                for (int r = 0; r < 4; ++r)
                    if (gj <= gi + r) acc[fr][fc][r] = 0.0f;
            }
        }
    }

    float* Srep = S8 + (size_t)band * NZ;   // band-local replica

    // row partials over this wave's 64 cols (C/D: col=lane&15, row=lq*4+reg)
    #pragma unroll
    for (int fr = 0; fr < 4; ++fr)
        #pragma unroll
        for (int r = 0; r < 4; ++r) {
            float s = acc[fr][0][r] + acc[fr][1][r] + acc[fr][2][r] + acc[fr][3][r];
            s += __shfl_xor(s, 1, 64);
            s += __shfl_xor(s, 2, 64);
            s += __shfl_xor(s, 4, 64);
            s += __shfl_xor(s, 8, 64);
            if (lm == 0)
                atomicAdd(&Srep[ti * BT + wr * 64 + fr * 16 + lq * 4 + r], s);
        }
    // col partials over this wave's 64 rows (symmetry: colsum feeds S too)
    #pragma unroll
    for (int fc = 0; fc < 4; ++fc) {
        float s = 0.0f;
        #pragma unroll
        for (int fr = 0; fr < 4; ++fr)
            #pragma unroll
            for (int r = 0; r < 4; ++r) s += acc[fr][fc][r];
        s += __shfl_xor(s, 16, 64);
        s += __shfl_xor(s, 32, 64);
        if (lq == 0)
            atomicAdd(&Srep[tj * BT + wc * 64 + fc * 16 + lm], s);
    }
}

// ---------------------------------------------------------------------------
// Kernel 3: per-row loss + mean. den = sum of 8 band replicas.
// ---------------------------------------------------------------------------
__global__ __launch_bounds__(256) void loss_kernel(
    const float* __restrict__ S8, const float* __restrict__ pos,
    float* __restrict__ out)
{
    const int i = blockIdx.x * 256 + threadIdx.x;
    float den1 = 0.0f, den2 = 0.0f;
    #pragma unroll
    for (int b = 0; b < NBAND; ++b) {
        den1 += S8[(size_t)b * NZ + i];
        den2 += S8[(size_t)b * NZ + N_ROWS + i];
    }
    float v = 0.5f * (logf(den1) + logf(den2)) - TAU_INV * pos[i];

    __shared__ float red[4];
    #pragma unroll
    for (int m = 1; m < 64; m <<= 1) v += __shfl_xor(v, m, 64);
    if ((threadIdx.x & 63) == 0) red[threadIdx.x >> 6] = v;
    __syncthreads();
    if (threadIdx.x == 0)
        atomicAdd(out, (red[0] + red[1] + red[2] + red[3]) * (1.0f / N_ROWS));
}

// ---------------------------------------------------------------------------
extern "C" void kernel_launch(void* const* d_in, const int* in_sizes, int n_in,
                              void* d_out, int out_size, void* d_ws, size_t ws_size,
                              hipStream_t stream)
{
    const float* z1 = (const float*)d_in[0];
    const float* z2 = (const float*)d_in[1];
    float* out = (float*)d_out;

    char* ws = (char*)d_ws;
    unsigned char* Z8 = (unsigned char*)ws;              // 16384*256 = 4 MB
    float* pos = (float*)(ws + 4194304);                 // 32 KB
    float* S8  = (float*)(ws + 4227072);                 // 8*16384*4 = 512 KB

    // normalize zeroes S8 and out; no memset nodes needed
    normalize_kernel<<<N_ROWS / 4, 256, 0, stream>>>(z1, z2, Z8, pos, S8, out);

    gram_kernel<<<NTRI, 256, 0, stream>>>(Z8, S8);

    loss_kernel<<<N_ROWS / 256, 256, 0, stream>>>(S8, pos, out);
}

// Round 13
// 159.581 us; speedup vs baseline: 3.5291x; 2.0024x over previous
//
#include <hip/hip_runtime.h>
#include <hip/hip_bf16.h>
#include <hip/hip_fp8.h>

#define N_ROWS 8192
#define NZ 16384           // rows of Z = [An; Bn]
#define DIM 256
#define TAU_INV 2.0f
#define BT 128             // block tile (square)
#define NTILE 128          // NZ / BT
#define NTRI (NTILE * (NTILE + 1) / 2)   // 8256 upper-tri tiles
#define NCHUNK 16

typedef float f32x4 __attribute__((ext_vector_type(4)));
typedef long lx2 __attribute__((ext_vector_type(2)));   // 16B = 2 fp8 MFMA operands

// ---------------------------------------------------------------------------
// Kernel 1: one WAVE per row. L2-normalize, scale by 16, quantize to OCP fp8
// e4m3, write Z8 K-INTERLEAVED: each 64B chunk stores its eight 8B K-groups
// as [g0 g4 g1 g5 g2 g6 g3 g7] so one 16B granule = operand pair (g, g+4)
// for two consecutive MFMA K-steps. Same permutation for A and B -> neutral.
// pos[i] = (1/256)*dot(quantized an, bn).
// ---------------------------------------------------------------------------
__global__ __launch_bounds__(256) void normalize_kernel(
    const float* __restrict__ z1, const float* __restrict__ z2,
    unsigned char* __restrict__ Z8, float* __restrict__ pos)
{
    const int tid = threadIdx.x;
    const int wave = tid >> 6;
    const int lane = tid & 63;
    const int row = blockIdx.x * 4 + wave;      // 0..8191

    const float4 a = ((const float4*)(z1 + (size_t)row * DIM))[lane];
    const float4 b = ((const float4*)(z2 + (size_t)row * DIM))[lane];

    auto wsum = [&](float v) -> float {
        #pragma unroll
        for (int m = 1; m < 64; m <<= 1) v += __shfl_xor(v, m, 64);
        return v;
    };

    const float na2 = wsum(a.x*a.x + a.y*a.y + a.z*a.z + a.w*a.w);
    const float nb2 = wsum(b.x*b.x + b.y*b.y + b.z*b.z + b.w*b.w);
    const float sa = 16.0f / sqrtf(na2);   // norms ~16; eps never binds
    const float sb = 16.0f / sqrtf(nb2);

    const float av[4] = {a.x*sa, a.y*sa, a.z*sa, a.w*sa};
    const float bv[4] = {b.x*sb, b.y*sb, b.z*sb, b.w*sb};
    unsigned char pa[4], pb[4];
    float qd = 0.0f;
    #pragma unroll
    for (int k = 0; k < 4; ++k) {
        __hip_fp8_e4m3 qa(av[k]);
        __hip_fp8_e4m3 qb(bv[k]);
        pa[k] = qa.__x; pb[k] = qb.__x;
        qd += float(qa) * float(qb);
    }
    // interleaved write: lane owns half (lane&1) of local K-group (lane>>1)&7
    const int g  = (lane >> 1) & 7;
    const int pp = ((g & 3) << 1) | (g >> 2);          // interleaved 8B slot
    const int off = (lane >> 4) * 64 + pp * 8 + (lane & 1) * 4;
    *(uchar4*)(Z8 + (size_t)row * DIM + off) = *(uchar4*)pa;
    *(uchar4*)(Z8 + (size_t)(N_ROWS + row) * DIM + off) = *(uchar4*)pb;

    qd = wsum(qd);
    if (lane == 0) pos[row] = qd * 0.00390625f;   // /256 -> quantized sim
}

// ---------------------------------------------------------------------------
// Kernel 2: symmetric fp8 gram, upper triangle, dense triangular grid.
// R12 compute core (measured: VALUBusy 19.8%, conflicts 0): BK=128, 2 K-steps,
// 3 barriers/tile, width-16 staging (16 instrs/wave/tile), b128 frag reads
// with tile-invariant addresses. 16B-granule XOR swizzle keyed by
// ((row&15)>>1) on both sides (staging via the pAE/pAO +-64 trick).
// Epilogue: exp2, diag mask, 512 coalesced part floats per block — NO
// atomics (R9/R12 lesson: device FP atomics RMW at the memory-side point,
// 170 MB traffic + serialization).
// ---------------------------------------------------------------------------
template <bool TWO_STAGE>
__global__ __launch_bounds__(256, 4) void gram_kernel(
    const unsigned char* __restrict__ Z,
    float* __restrict__ part, float* __restrict__ S)
{
    // XCD band remap (8256 = 8 * 1032), then triangular decode.
    const int bid = (blockIdx.x & 7) * (NTRI / 8) + (blockIdx.x >> 3);
    int ti = (int)((257.0f - sqrtf(66049.0f - 8.0f * (float)bid)) * 0.5f);
    ti = ti < 0 ? 0 : (ti > 127 ? 127 : ti);
    while (ti * (257 - ti) / 2 > bid) --ti;
    while ((ti + 1) * (256 - ti) / 2 <= bid) ++ti;
    const int tj = ti + (bid - ti * (257 - ti) / 2);
    const bool diag = (ti == tj);

    __shared__ unsigned char Ls[32768];   // A: [0,16K), B: [16K,32K)

    const int tid  = threadIdx.x;
    const int wave = tid >> 6;
    const int lane = tid & 63;
    const int wr = wave >> 1, wc = wave & 1;
    const int lm = lane & 15, lq = lane >> 4;

    // ---- staging lane geometry (width-16: 1KB instr = 8 rows x 8 granules)
    const int r8 = lane >> 3;                   // row within 8-row group
    const int pg = lane & 7;                    // LDS granule slot
    const int G0 = pg ^ (r8 >> 1);              // global granule, even instrs
    const int dlt = 64 - ((G0 & 4) << 5);       // odd instrs: granule G0^4
    const unsigned char* pAE =
        Z + (size_t)(ti * BT + wave * 32 + r8) * DIM + (G0 << 4);
    const unsigned char* pBE =
        Z + (size_t)(tj * BT + wave * 32 + r8) * DIM + (G0 << 4);
    const unsigned char* pAO = pAE + dlt;
    const unsigned char* pBO = pBE + dlt;

    // ---- frag-read bases (invariant across the whole tile)
    const int s0 = (lq ^ (lm >> 1)) << 4;       // slot of granule lq
    const int s1 = s0 ^ 64;                     // slot of granule lq^4
    const unsigned char* LA0 = Ls + wr * 8192 + lm * 128 + s0;
    const unsigned char* LA1 = Ls + wr * 8192 + lm * 128 + s1;
    const unsigned char* LB0 = Ls + 16384 + wc * 8192 + lm * 128 + s0;
    const unsigned char* LB1 = Ls + 16384 + wc * 8192 + lm * 128 + s1;

    f32x4 acc[4][4] = {};

    #pragma unroll
    for (int kh = 0; kh < 2; ++kh) {
        if (kh) __syncthreads();        // protect LDS reads of prev k-half
        #pragma unroll
        for (int c = 0; c < 4; ++c) {   // 4 A + 4 B instrs per wave
            const int ld = (wave * 4 + c) * 1024;       // wave-uniform dest
            const unsigned char* ga = ((c & 1) ? pAO : pAE) + c * 2048 + kh * 128;
            const unsigned char* gb = ((c & 1) ? pBO : pBE) + c * 2048 + kh * 128;
            __builtin_amdgcn_global_load_lds(
                (const __attribute__((address_space(1))) void*)ga,
                (__attribute__((address_space(3))) void*)(Ls + ld), 16, 0, 0);
            __builtin_amdgcn_global_load_lds(
                (const __attribute__((address_space(1))) void*)gb,
                (__attribute__((address_space(3))) void*)(Ls + 16384 + ld), 16, 0, 0);
        }
        __syncthreads();

        lx2 aP[4], bP[4];
        #pragma unroll
        for (int f = 0; f < 4; ++f) {
            aP[f] = *(const lx2*)(LA0 + f * 2048);
            bP[f] = *(const lx2*)(LB0 + f * 2048);
        }
        #pragma unroll
        for (int fr = 0; fr < 4; ++fr)
            #pragma unroll
            for (int fc = 0; fc < 4; ++fc) {
                acc[fr][fc] = __builtin_amdgcn_mfma_f32_16x16x32_fp8_fp8(
                    aP[fr].x, bP[fc].x, acc[fr][fc], 0, 0, 0);
                acc[fr][fc] = __builtin_amdgcn_mfma_f32_16x16x32_fp8_fp8(
                    aP[fr].y, bP[fc].y, acc[fr][fc], 0, 0, 0);
            }
        #pragma unroll
        for (int f = 0; f < 4; ++f) {
            aP[f] = *(const lx2*)(LA1 + f * 2048);
            bP[f] = *(const lx2*)(LB1 + f * 2048);
        }
        #pragma unroll
        for (int fr = 0; fr < 4; ++fr)
            #pragma unroll
            for (int fc = 0; fc < 4; ++fc) {
                acc[fr][fc] = __builtin_amdgcn_mfma_f32_16x16x32_fp8_fp8(
                    aP[fr].x, bP[fc].x, acc[fr][fc], 0, 0, 0);
                acc[fr][fc] = __builtin_amdgcn_mfma_f32_16x16x32_fp8_fp8(
                    aP[fr].y, bP[fc].y, acc[fr][fc], 0, 0, 0);
            }
    }
    // epilogue is LDS-free: no trailing barrier

    // dot = 256*sim; exp(2*sim) = exp2(dot * 2*log2(e)/256)
    const float SC = 2.8853900817779268f / 256.0f;
    #pragma unroll
    for (int fr = 0; fr < 4; ++fr)
        #pragma unroll
        for (int fc = 0; fc < 4; ++fc)
            #pragma unroll
            for (int r = 0; r < 4; ++r)
                acc[fr][fc][r] = exp2f(acc[fr][fc][r] * SC);

    if (diag) {   // zero at-or-below-diagonal (each pair counted once)
        #pragma unroll
        for (int fr = 0; fr < 4; ++fr) {
            const int gi = wr * 64 + fr * 16 + lq * 4;
            #pragma unroll
            for (int fc = 0; fc < 4; ++fc) {
                const int gj = wc * 64 + fc * 16 + lm;
                #pragma unroll
                for (int r = 0; r < 4; ++r)
                    if (gj <= gi + r) acc[fr][fc][r] = 0.0f;
            }
        }
    }

    float* dst = TWO_STAGE ? (part + (size_t)bid * 512) : nullptr;

    // row partials over this wave's 64 cols (C/D: col=lane&15, row=lq*4+reg)
    #pragma unroll
    for (int fr = 0; fr < 4; ++fr)
        #pragma unroll
        for (int r = 0; r < 4; ++r) {
            float s = acc[fr][0][r] + acc[fr][1][r] + acc[fr][2][r] + acc[fr][3][r];
            s += __shfl_xor(s, 1, 64);
            s += __shfl_xor(s, 2, 64);
            s += __shfl_xor(s, 4, 64);
            s += __shfl_xor(s, 8, 64);
            if (lm == 0) {
                const int rr = wr * 64 + fr * 16 + lq * 4 + r;
                if (TWO_STAGE) dst[wc * 128 + rr] = s;
                else atomicAdd(&S[ti * BT + rr], s);
            }
        }
    // col partials over this wave's 64 rows (symmetry: colsum feeds S too)
    #pragma unroll
    for (int fc = 0; fc < 4; ++fc) {
        float s = 0.0f;
        #pragma unroll
        for (int fr = 0; fr < 4; ++fr)
            #pragma unroll
            for (int r = 0; r < 4; ++r) s += acc[fr][fc][r];
        s += __shfl_xor(s, 16, 64);
        s += __shfl_xor(s, 32, 64);
        if (lq == 0) {
            const int cc = wc * 64 + fc * 16 + lm;
            if (TWO_STAGE) dst[256 + wr * 128 + cc] = s;
            else atomicAdd(&S[tj * BT + cc], s);
        }
    }
}

// ---------------------------------------------------------------------------
// Kernel 3: parallel partial gather. grid (NZ/256, NCHUNK). Each Z-row has
// exactly 258 strips: row-side blocks (tr,tj) tj=tr..127 (slots {0,128}+rr),
// col-side blocks (ti,tr) ti=0..tr (slots 256+{0,128}+rr). All coalesced.
// Also zeroes out[0].
// ---------------------------------------------------------------------------
__global__ __launch_bounds__(256) void reduce_kernel(
    const float* __restrict__ part, float* __restrict__ S2,
    float* __restrict__ out)
{
    const int chunk = blockIdx.y;
    const int tid = threadIdx.x;
    const int r = blockIdx.x * 256 + tid;       // Z row
    const int tr = r >> 7, rr = r & 127;
    const int baseRow = tr * (257 - tr) / 2;
    const int cntRow = 2 * (128 - tr);

    if (chunk == 0 && r == 0) out[0] = 0.0f;

    float s = 0.0f;
    for (int m = chunk; m < 258; m += NCHUNK) {
        size_t addr;
        if (m < cntRow) {
            const int bb = baseRow + (m >> 1);
            addr = (size_t)bb * 512 + (m & 1) * 128 + rr;
        } else {
            const int m2 = m - cntRow;
            const int tiq = m2 >> 1;
            const int bb = tiq * (257 - tiq) / 2 + (tr - tiq);
            addr = (size_t)bb * 512 + 256 + (m2 & 1) * 128 + rr;
        }
        s += part[addr];
    }
    S2[(size_t)chunk * NZ + r] = s;
}

// ---------------------------------------------------------------------------
// Kernel 4: loss + mean (two-stage path).
// ---------------------------------------------------------------------------
__global__ __launch_bounds__(256) void loss2_kernel(
    const float* __restrict__ S2, const float* __restrict__ pos,
    float* __restrict__ out)
{
    const int i = blockIdx.x * 256 + threadIdx.x;
    float den1 = 0.0f, den2 = 0.0f;
    #pragma unroll
    for (int c = 0; c < NCHUNK; ++c) {
        den1 += S2[(size_t)c * NZ + i];
        den2 += S2[(size_t)c * NZ + N_ROWS + i];
    }
    float v = 0.5f * (logf(den1) + logf(den2)) - TAU_INV * pos[i];

    __shared__ float red[4];
    #pragma unroll
    for (int m = 1; m < 64; m <<= 1) v += __shfl_xor(v, m, 64);
    if ((threadIdx.x & 63) == 0) red[threadIdx.x >> 6] = v;
    __syncthreads();
    if (threadIdx.x == 0)
        atomicAdd(out, (red[0] + red[1] + red[2] + red[3]) * (1.0f / N_ROWS));
}

// Fallback loss (atomic path, only if ws too small — never expected).
__global__ __launch_bounds__(256) void loss_kernel(
    const float* __restrict__ S, const float* __restrict__ pos,
    float* __restrict__ out)
{
    const int i = blockIdx.x * 256 + threadIdx.x;
    float v = 0.5f * (logf(S[i]) + logf(S[N_ROWS + i])) - TAU_INV * pos[i];

    __shared__ float red[4];
    #pragma unroll
    for (int m = 1; m < 64; m <<= 1) v += __shfl_xor(v, m, 64);
    if ((threadIdx.x & 63) == 0) red[threadIdx.x >> 6] = v;
    __syncthreads();
    if (threadIdx.x == 0)
        atomicAdd(out, (red[0] + red[1] + red[2] + red[3]) * (1.0f / N_ROWS));
}

// ---------------------------------------------------------------------------
extern "C" void kernel_launch(void* const* d_in, const int* in_sizes, int n_in,
                              void* d_out, int out_size, void* d_ws, size_t ws_size,
                              hipStream_t stream)
{
    const float* z1 = (const float*)d_in[0];
    const float* z2 = (const float*)d_in[1];
    float* out = (float*)d_out;

    char* ws = (char*)d_ws;
    unsigned char* Z8 = (unsigned char*)ws;              // 16384*256 = 4 MB
    float* pos  = (float*)(ws + 4194304);                // 32 KB
    float* S2   = (float*)(ws + 4227072);                // 16*16384*4 = 1 MB
    float* part = (float*)(ws + 5275648);                // 8256*512*4 = 16.9 MB
    const size_t need = 5275648 + (size_t)NTRI * 512 * 4;

    normalize_kernel<<<N_ROWS / 4, 256, 0, stream>>>(z1, z2, Z8, pos);

    if (ws_size >= need) {
        gram_kernel<true><<<NTRI, 256, 0, stream>>>(Z8, part, nullptr);
        dim3 rg(NZ / 256, NCHUNK);
        reduce_kernel<<<rg, 256, 0, stream>>>(part, S2, out);   // zeroes out
        loss2_kernel<<<N_ROWS / 256, 256, 0, stream>>>(S2, pos, out);
    } else {
        hipMemsetAsync(S2, 0, NZ * sizeof(float), stream);
        hipMemsetAsync(out, 0, sizeof(float), stream);
        gram_kernel<false><<<NTRI, 256, 0, stream>>>(Z8, nullptr, S2);
        loss_kernel<<<N_ROWS / 256, 256, 0, stream>>>(S2, pos, out);
    }
}